// Round 14
// baseline (385.704 us; speedup 1.0000x reference)
//
#include <hip/hip_runtime.h>
#include <hip/hip_fp16.h>

// ---------------------------------------------------------------------------
// 2-layer GCN via device-built CSR + L2-resident scaled gather tables.
// CSR build (deterministic two-level counting sort, no global atomics):
//   k_hist -> k_scanA1/A2 (segmented) -> k_scanB -> k_scanA3 -> k_bin ->
//   k_bucket (rp/dinv/adj).  Bucket = 1024 dst nodes (write-window fix).
// k_bucket uses a wave-shuffle scan (4 barriers vs 20 naive) + 4-way ILP
// (round-13: 63 us, 20 barriers of a 16-wave block dominated).
// k_bin: 8-way independent chains (round-13: 63 us at 4-way).
// Layers (aggregate-first on layer 2; aggregation is linear):
//   h1s = dinv * (x@W1)          fp16 lo/hi 8-ch tables (3.2 MB -> L2-fit)
//   z1s = dinv * relu(agg+b1)    fp16 lo/hi
//   pre = agg(z1s)               f32 lo/hi
//   out = pre @ W2 + b2
// Gathers (k_gather4): thread = (node, channel-pair), __half2 loads -> 16
// row-loads in flight per wave; dinv folded into tables (1 random row read
// per edge). k_mm1 LDS-staged. Region R = bbuf then {h1s,z1s,pre}.
// ---------------------------------------------------------------------------

#define TPB 256
#define BINT 256
#define SEGROWS 64
#define BUCKSH 10                 // log2(nodes per bucket)
#define BUCKN (1 << BUCKSH)       // 1024 nodes per bucket
#define MMN 32                    // nodes per mm1 tile

__device__ __forceinline__ int clampi(int v, int n) {
    return v < 0 ? 0 : (v >= n ? n - 1 : v);
}

// --- per-block LDS histogram over contiguous edge range ------------------
__global__ __launch_bounds__(BINT) void k_hist(const int* __restrict__ dst,
                                               int E, int n, int nbuck,
                                               int chunk,
                                               int* __restrict__ hist) {
    __shared__ int lh[256];
    const int b = blockIdx.x;
    const int t = threadIdx.x;
    lh[t] = 0;
    __syncthreads();
    const int start = b * chunk;
    const int end = min(E, start + chunk);
    int i = start + t;
    for (; i + 3 * BINT < end; i += 4 * BINT) {
        int d0 = clampi(dst[i], n);
        int d1 = clampi(dst[i + BINT], n);
        int d2 = clampi(dst[i + 2 * BINT], n);
        int d3 = clampi(dst[i + 3 * BINT], n);
        atomicAdd(&lh[d0 >> BUCKSH], 1);
        atomicAdd(&lh[d1 >> BUCKSH], 1);
        atomicAdd(&lh[d2 >> BUCKSH], 1);
        atomicAdd(&lh[d3 >> BUCKSH], 1);
    }
    for (; i < end; i += BINT) atomicAdd(&lh[clampi(dst[i], n) >> BUCKSH], 1);
    __syncthreads();
    for (int k = t; k < nbuck; k += BINT) hist[b * nbuck + k] = lh[k];
}

// --- segmented column scan stage 1: per-segment column sums --------------
__global__ void k_scanA1(const int* __restrict__ hist, int nbuck,
                         int* __restrict__ segsum) {
    int k = blockIdx.x * blockDim.x + threadIdx.x;
    int seg = blockIdx.y;
    if (k >= nbuck) return;
    const int* row = hist + (size_t)seg * SEGROWS * nbuck + k;
    int sum = 0;
#pragma unroll
    for (int b = 0; b < SEGROWS; ++b) sum += row[(size_t)b * nbuck];
    segsum[seg * nbuck + k] = sum;
}

// --- stage 2: serial scan over segments (nseg <= 32) + colsum ------------
__global__ void k_scanA2(int* __restrict__ segsum, int nbuck, int nseg,
                         int* __restrict__ colsum) {
    int k = blockIdx.x * blockDim.x + threadIdx.x;
    if (k >= nbuck) return;
    int run = 0;
    for (int sg = 0; sg < nseg; ++sg) {
        int v = segsum[sg * nbuck + k];
        segsum[sg * nbuck + k] = run;
        run += v;
    }
    colsum[k] = run;
}

// --- exclusive scan of colsum -> bstart[0..nbuck] ------------------------
__global__ void k_scanB(const int* __restrict__ colsum, int nbuck, int E,
                        int* __restrict__ bstart) {
    __shared__ int s[256];
    const int t = threadIdx.x;
    int loc[4];
    int a = 0;
#pragma unroll
    for (int i = 0; i < 4; ++i) {
        int idx = 4 * t + i;
        loc[i] = (idx < nbuck) ? colsum[idx] : 0;
        a += loc[i];
    }
    s[t] = a;
    __syncthreads();
#pragma unroll
    for (int off = 1; off < 256; off <<= 1) {
        int v = (t >= off) ? s[t - off] : 0;
        __syncthreads();
        s[t] += v;
        __syncthreads();
    }
    int base = s[t] - a;
#pragma unroll
    for (int i = 0; i < 4; ++i) {
        int idx = 4 * t + i;
        if (idx < nbuck) bstart[idx] = base;
        base += loc[i];
    }
    if (t == 255) bstart[nbuck] = E;
}

// --- stage 3: rewrite hist rows to global exclusive prefix ---------------
__global__ void k_scanA3(int* __restrict__ hist, int nbuck,
                         const int* __restrict__ segsum) {
    int k = blockIdx.x * blockDim.x + threadIdx.x;
    int seg = blockIdx.y;
    if (k >= nbuck) return;
    int run = segsum[seg * nbuck + k];
    int* row = hist + (size_t)seg * SEGROWS * nbuck + k;
#pragma unroll
    for (int b = 0; b < SEGROWS; ++b) {
        int v = row[(size_t)b * nbuck];
        row[(size_t)b * nbuck] = run;
        run += v;
    }
}

// --- binning: LDS cursors, LDS atomics only; 8-way ILP -------------------
__global__ __launch_bounds__(BINT) void k_bin(const int* __restrict__ src,
                                              const int* __restrict__ dst,
                                              int E, int n, int nbuck,
                                              int chunk,
                                              const int* __restrict__ hist,
                                              const int* __restrict__ bstart,
                                              int* __restrict__ bbuf) {
    __shared__ int lcur[256];
    const int b = blockIdx.x;
    const int t = threadIdx.x;
    for (int k = t; k < nbuck; k += BINT)
        lcur[k] = bstart[k] + hist[b * nbuck + k];
    __syncthreads();
    const int start = b * chunk;
    const int end = min(E, start + chunk);
    int i = start + t;
    for (; i + 7 * BINT < end; i += 8 * BINT) {
        int s[8], d[8], p[8];
#pragma unroll
        for (int q = 0; q < 8; ++q) s[q] = clampi(src[i + q * BINT], n);
#pragma unroll
        for (int q = 0; q < 8; ++q) d[q] = clampi(dst[i + q * BINT], n);
#pragma unroll
        for (int q = 0; q < 8; ++q)
            p[q] = atomicAdd(&lcur[d[q] >> BUCKSH], 1);
#pragma unroll
        for (int q = 0; q < 8; ++q)
            bbuf[p[q]] = ((d[q] & (BUCKN - 1)) << 18) | s[q];
    }
    for (; i < end; i += BINT) {
        int s0 = clampi(src[i], n);
        int d0 = clampi(dst[i], n);
        int p0 = atomicAdd(&lcur[d0 >> BUCKSH], 1);
        bbuf[p0] = ((d0 & (BUCKN - 1)) << 18) | s0;
    }
}

// --- per-bucket (1024 nodes, 1024 thr): hist -> wave-scan -> scatter -----
__global__ __launch_bounds__(1024) void k_bucket(const int* __restrict__ bbuf,
                                                 const int* __restrict__ bstart,
                                                 int n, int* __restrict__ rp,
                                                 float* __restrict__ dinv,
                                                 int* __restrict__ adj) {
    __shared__ int lcnt[1024];
    __shared__ int wsum[16];
    const int b = blockIdx.x;
    const int t = threadIdx.x;
    const int start = bstart[b];
    const int end = bstart[b + 1];

    lcnt[t] = 0;
    __syncthreads();
    // histogram, 4-way ILP
    {
        int i = start + t;
        for (; i + 3 * 1024 < end; i += 4 * 1024) {
            int p0 = bbuf[i], p1 = bbuf[i + 1024], p2 = bbuf[i + 2048],
                p3 = bbuf[i + 3072];
            atomicAdd(&lcnt[((unsigned)p0) >> 18], 1);
            atomicAdd(&lcnt[((unsigned)p1) >> 18], 1);
            atomicAdd(&lcnt[((unsigned)p2) >> 18], 1);
            atomicAdd(&lcnt[((unsigned)p3) >> 18], 1);
        }
        for (; i < end; i += 1024)
            atomicAdd(&lcnt[((unsigned)bbuf[i]) >> 18], 1);
    }
    __syncthreads();

    const int c = lcnt[t];
    // wave-level inclusive scan (register shuffles, no barriers)
    int val = c;
#pragma unroll
    for (int off = 1; off < 64; off <<= 1) {
        int vv = __shfl_up(val, off, 64);
        if ((t & 63) >= off) val += vv;
    }
    if ((t & 63) == 63) wsum[t >> 6] = val;
    __syncthreads();
    if (t == 0) {
        int run = 0;
#pragma unroll
        for (int w = 0; w < 16; ++w) {
            int v = wsum[w];
            wsum[w] = run;
            run += v;
        }
    }
    __syncthreads();
    const int incl = val + wsum[t >> 6];  // inclusive prefix over block
    const int v = (b << BUCKSH) + t;
    if (v < n) {
        rp[v] = start + incl;  // inclusive row end
        dinv[v] = rsqrtf((float)(c + 1));
    }
    lcnt[t] = start + incl - c;  // write cursor (own slot only)
    __syncthreads();

    // clustered scatter, 4-way ILP
    {
        int i = start + t;
        for (; i + 3 * 1024 < end; i += 4 * 1024) {
            int p0 = bbuf[i], p1 = bbuf[i + 1024], p2 = bbuf[i + 2048],
                p3 = bbuf[i + 3072];
            int q0 = atomicAdd(&lcnt[((unsigned)p0) >> 18], 1);
            int q1 = atomicAdd(&lcnt[((unsigned)p1) >> 18], 1);
            int q2 = atomicAdd(&lcnt[((unsigned)p2) >> 18], 1);
            int q3 = atomicAdd(&lcnt[((unsigned)p3) >> 18], 1);
            adj[q0] = p0 & 0x3FFFF;
            adj[q1] = p1 & 0x3FFFF;
            adj[q2] = p2 & 0x3FFFF;
            adj[q3] = p3 & 0x3FFFF;
        }
        for (; i < end; i += 1024) {
            int p = bbuf[i];
            int q = atomicAdd(&lcnt[((unsigned)p) >> 18], 1);
            adj[q] = p & 0x3FFFF;
        }
    }
}

// --- h1s = dinv*(x@W1): LDS-staged tile (32 nodes), 512 thr --------------
__global__ __launch_bounds__(512) void k_mm1(const float* __restrict__ x,
                                             const float* __restrict__ W,
                                             const float* __restrict__ dinv,
                                             int n, __half* __restrict__ hlo,
                                             __half* __restrict__ hhi) {
    __shared__ float Ws[128 * 16];
    __shared__ float xs[MMN * 132];
    const int t = threadIdx.x;
    for (int i = t; i < 128 * 16; i += 512) Ws[i] = W[i];
    const int node0 = blockIdx.x * MMN;
    {
        const float4* xg = (const float4*)(x + (size_t)node0 * 128);
#pragma unroll
        for (int it = 0; it < 2; ++it) {
            int idx = it * 512 + t;  // float4 index in tile, 0..1023
            int row = idx >> 5;
            int c4 = idx & 31;
            if (node0 + row < n) {
                float4 v = xg[(size_t)row * 32 + c4];
                float* dp = &xs[row * 132 + c4 * 4];
                dp[0] = v.x;
                dp[1] = v.y;
                dp[2] = v.z;
                dp[3] = v.w;
            }
        }
    }
    __syncthreads();
    const int node = node0 + (t >> 4);
    const int c = t & 15;
    if (node < n) {
        const float4* xr4 = (const float4*)&xs[(t >> 4) * 132];
        float acc = 0.f;
#pragma unroll
        for (int q = 0; q < 32; ++q) {
            float4 xv = xr4[q];
            acc += xv.x * Ws[(4 * q + 0) * 16 + c] +
                   xv.y * Ws[(4 * q + 1) * 16 + c] +
                   xv.z * Ws[(4 * q + 2) * 16 + c] +
                   xv.w * Ws[(4 * q + 3) * 16 + c];
        }
        __half hv = __float2half(dinv[node] * acc);
        if (c < 8)
            hlo[(size_t)node * 8 + c] = hv;
        else
            hhi[(size_t)node * 8 + (c - 8)] = hv;
    }
}

// --- CSR gather, thread = (node, channel-pair), __half2, 8-deep ILP ------
template <bool L1>
__global__ void k_gather4(const int* __restrict__ rp,
                          const int* __restrict__ adj,
                          const float* __restrict__ dinv,
                          const __half* __restrict__ hs,
                          const float* __restrict__ bias, int ch0,
                          void* __restrict__ o, int n) {
    long long total = (long long)n * 4;
    long long i = (long long)blockIdx.x * blockDim.x + threadIdx.x;
    long long stride = (long long)gridDim.x * blockDim.x;
    for (; i < total; i += stride) {
        int v = (int)(i >> 2);
        int jp = (int)(i & 3);
        int start = (v == 0) ? 0 : rp[v - 1];
        int end = rp[v];
        float ax0 = 0.f, ay0 = 0.f, ax1 = 0.f, ay1 = 0.f;
        float ax2 = 0.f, ay2 = 0.f, ax3 = 0.f, ay3 = 0.f;
        float ax4 = 0.f, ay4 = 0.f, ax5 = 0.f, ay5 = 0.f;
        float ax6 = 0.f, ay6 = 0.f, ax7 = 0.f, ay7 = 0.f;
        int k = start;
        for (; k + 7 < end; k += 8) {
            int s0 = adj[k], s1 = adj[k + 1], s2 = adj[k + 2], s3 = adj[k + 3];
            int s4 = adj[k + 4], s5 = adj[k + 5], s6 = adj[k + 6],
                s7 = adj[k + 7];
            __half2 h0 = *(const __half2*)(hs + (size_t)s0 * 8 + jp * 2);
            __half2 h1 = *(const __half2*)(hs + (size_t)s1 * 8 + jp * 2);
            __half2 h2 = *(const __half2*)(hs + (size_t)s2 * 8 + jp * 2);
            __half2 h3 = *(const __half2*)(hs + (size_t)s3 * 8 + jp * 2);
            __half2 h4 = *(const __half2*)(hs + (size_t)s4 * 8 + jp * 2);
            __half2 h5 = *(const __half2*)(hs + (size_t)s5 * 8 + jp * 2);
            __half2 h6 = *(const __half2*)(hs + (size_t)s6 * 8 + jp * 2);
            __half2 h7 = *(const __half2*)(hs + (size_t)s7 * 8 + jp * 2);
            ax0 += __low2float(h0); ay0 += __high2float(h0);
            ax1 += __low2float(h1); ay1 += __high2float(h1);
            ax2 += __low2float(h2); ay2 += __high2float(h2);
            ax3 += __low2float(h3); ay3 += __high2float(h3);
            ax4 += __low2float(h4); ay4 += __high2float(h4);
            ax5 += __low2float(h5); ay5 += __high2float(h5);
            ax6 += __low2float(h6); ay6 += __high2float(h6);
            ax7 += __low2float(h7); ay7 += __high2float(h7);
        }
        for (; k < end; ++k) {
            __half2 h = *(const __half2*)(hs + (size_t)adj[k] * 8 + jp * 2);
            ax0 += __low2float(h);
            ay0 += __high2float(h);
        }
        __half2 hself = *(const __half2*)(hs + (size_t)v * 8 + jp * 2);
        float dv = dinv[v];
        float sx = (((ax0 + ax1) + (ax2 + ax3)) + ((ax4 + ax5) + (ax6 + ax7))) +
                   __low2float(hself);
        float sy = (((ay0 + ay1) + (ay2 + ay3)) + ((ay4 + ay5) + (ay6 + ay7))) +
                   __high2float(hself);
        float vx = dv * sx;
        float vy = dv * sy;
        if (L1) {
            vx = fmaxf(vx + bias[ch0 + 2 * jp], 0.f);
            vy = fmaxf(vy + bias[ch0 + 2 * jp + 1], 0.f);
            *(__half2*)((__half*)o + (size_t)v * 8 + jp * 2) =
                __floats2half2_rn(dv * vx, dv * vy);
        } else {
            *(float2*)((float*)o + (size_t)v * 8 + jp * 2) =
                make_float2(vx, vy);
        }
    }
}

// --- out = [preL|preH] @ W2 + b2 -----------------------------------------
__global__ void k_out(const float* __restrict__ preL,
                      const float* __restrict__ preH,
                      const float* __restrict__ W2,
                      const float* __restrict__ b2, float* __restrict__ out,
                      int n) {
    __shared__ float Ws[16 * 32];
    for (int i = threadIdx.x; i < 16 * 32; i += blockDim.x) Ws[i] = W2[i];
    __syncthreads();
    long long total = (long long)n * 32;
    long long i = (long long)blockIdx.x * blockDim.x + threadIdx.x;
    long long stride = (long long)gridDim.x * blockDim.x;
    for (; i < total; i += stride) {
        int v = (int)(i >> 5);
        int c = (int)(i & 31);
        const float* pl = preL + (size_t)v * 8;
        const float* ph = preH + (size_t)v * 8;
        float acc = b2[c];
#pragma unroll
        for (int j = 0; j < 8; ++j) acc += pl[j] * Ws[j * 32 + c];
#pragma unroll
        for (int j = 0; j < 8; ++j) acc += ph[j] * Ws[(8 + j) * 32 + c];
        out[i] = acc;
    }
}

static inline int blocks_for(long long total) {
    return (int)((total + TPB - 1) / TPB);
}

extern "C" void kernel_launch(void* const* d_in, const int* in_sizes, int n_in,
                              void* d_out, int out_size, void* d_ws,
                              size_t ws_size, hipStream_t stream) {
    const float* x = (const float*)d_in[0];
    const int* ei = (const int*)d_in[1];
    const float* W1 = (const float*)d_in[2];
    const float* b1 = (const float*)d_in[3];
    const float* W2 = (const float*)d_in[4];
    const float* b2 = (const float*)d_in[5];
    float* out = (float*)d_out;

    const int n = in_sizes[0] / 128;  // 200000 nodes
    const int E = in_sizes[1] / 2;    // 6400000 edges
    const int* src = ei;
    const int* dst = ei + E;
    const int nbuck = (n + BUCKN - 1) / BUCKN;  // 196 (<= 256 required)

    // base workspace: dinv n f32 | rp n i32 | adj E i32 | R = E i32 (25.6 MB)
    char* ws = (char*)d_ws;
    float* dinv = (float*)ws;
    int* rp = (int*)(ws + (size_t)n * 4);
    int* adj = (int*)(ws + (size_t)n * 8);
    char* R = ws + (size_t)n * 8 + (size_t)E * 4;
    size_t base_bytes = (size_t)n * 8 + (size_t)E * 8;

    // choose NBB by available scratch (hist = NBB*nbuck*4 after R)
    auto need = [&](int nbb) {
        return base_bytes +
               ((size_t)nbb + (size_t)nbb / SEGROWS + 2) * nbuck * 4 + 8192;
    };
    const int NBB =
        (ws_size >= need(2048)) ? 2048 : ((ws_size >= need(1024)) ? 1024 : 512);
    const int nseg = NBB / SEGROWS;
    const int chunk = (E + NBB - 1) / NBB;

    int* hist = (int*)(R + (size_t)E * 4);
    int* segsum = hist + (size_t)NBB * nbuck;
    int* colsum = segsum + (size_t)nseg * nbuck;
    int* bstart = colsum + nbuck;
    int* bbuf = (int*)R;  // E ints, dead before k_mm1 runs

    // region R after build: h1sL/h1sH/z1sL/z1sH (n*8 half) + preL/preH (n*8 f32)
    __half* h1sL = (__half*)R;
    __half* h1sH = (__half*)(R + (size_t)n * 16);
    __half* z1sL = (__half*)(R + (size_t)n * 32);
    __half* z1sH = (__half*)(R + (size_t)n * 48);
    float* preL = (float*)(R + (size_t)n * 64);
    float* preH = (float*)(R + (size_t)n * 96);

    const int cb = (nbuck + 255) / 256;  // 1

    // --- CSR build (no global atomics) ---
    k_hist<<<NBB, BINT, 0, stream>>>(dst, E, n, nbuck, chunk, hist);
    k_scanA1<<<dim3(cb, nseg), 256, 0, stream>>>(hist, nbuck, segsum);
    k_scanA2<<<cb, 256, 0, stream>>>(segsum, nbuck, nseg, colsum);
    k_scanB<<<1, 256, 0, stream>>>(colsum, nbuck, E, bstart);
    k_scanA3<<<dim3(cb, nseg), 256, 0, stream>>>(hist, nbuck, segsum);
    k_bin<<<NBB, BINT, 0, stream>>>(src, dst, E, n, nbuck, chunk, hist, bstart,
                                    bbuf);
    k_bucket<<<nbuck, 1024, 0, stream>>>(bbuf, bstart, n, rp, dinv, adj);

    // --- layer 1 ---
    k_mm1<<<(n + MMN - 1) / MMN, 512, 0, stream>>>(x, W1, dinv, n, h1sL, h1sH);
    k_gather4<true><<<blocks_for((long long)n * 4), TPB, 0, stream>>>(
        rp, adj, dinv, h1sL, b1, 0, z1sL, n);
    k_gather4<true><<<blocks_for((long long)n * 4), TPB, 0, stream>>>(
        rp, adj, dinv, h1sH, b1, 8, z1sH, n);

    // --- layer 2 ---
    k_gather4<false><<<blocks_for((long long)n * 4), TPB, 0, stream>>>(
        rp, adj, dinv, z1sL, nullptr, 0, preL, n);
    k_gather4<false><<<blocks_for((long long)n * 4), TPB, 0, stream>>>(
        rp, adj, dinv, z1sH, nullptr, 8, preH, n);
    k_out<<<blocks_for((long long)n * 32), TPB, 0, stream>>>(preL, preH, W2, b2,
                                                             out, n);
}